// Round 7
// baseline (25123.059 us; speedup 1.0000x reference)
//
#include <hip/hip_runtime.h>

// ============================================================================
// 8-layer alternating-direction masked LSTM stack + embed + dense/softmax.
// R7: LDS-resident Wh. Grid = 32 blocks = 4 batch-groups x 8 col-eighths.
// Per block: Wh slice (32 h-cols x 4 gates x 256 k = 64 KB) staged in LDS
// ONCE -> zero per-step weight streaming (the R2-R6 hidden killer: compiler
// rematerialized/spilled "register-resident" weights -> 256-512KB/step L2
// stream). Per step: 8 MFMA/wave, z transposed via LDS, ONE gate value per
// thread, h all-gathered across the 8 col-blocks via global hx + per-wave
// release flags (R4-proven protocol). Two lgkm-only barriers per step.
// ============================================================================

typedef _Float16 f16;
typedef _Float16 f16x8 __attribute__((ext_vector_type(8)));
typedef _Float16 f16x4 __attribute__((ext_vector_type(4)));
typedef float    f32x4 __attribute__((ext_vector_type(4)));

#define DEVI static __device__ __forceinline__

DEVI float fast_sigmoid(float x) {
  return __builtin_amdgcn_rcpf(1.f + __builtin_amdgcn_exp2f(-1.44269504f * x));
}
DEVI float fast_tanh(float x) {
  return 1.f - 2.f * __builtin_amdgcn_rcpf(1.f + __builtin_amdgcn_exp2f(2.88539008f * x));
}

// ---------------------------------------------------------------------------
// pack_frags: dst frag layout [L][kk][nt][lane][8 f16].
// B-frag (16x16x32): lane l holds B[k=kk*32+(l>>4)*8+e][col=nt*16+(l&15)]
// ---------------------------------------------------------------------------
__global__ void pack_frags(const float* __restrict__ src, f16* __restrict__ dst, int nct) {
  const int idx  = blockIdx.x * 256 + threadIdx.x;
  const int lane = idx & 63;
  const int f    = idx >> 6;
  const int nt   = f % nct;
  const int g2   = f / nct;
  const int kk   = g2 & 7;
  const int L    = g2 >> 3;
  const int ncols = nct * 16;
  const float* s = src + (size_t)(L * 256 + kk * 32 + (lane >> 4) * 8) * ncols + nt * 16 + (lane & 15);
  f16x8 v;
#pragma unroll
  for (int e = 0; e < 8; ++e) v[e] = (f16)s[(size_t)e * ncols];
  *(f16x8*)(dst + (size_t)idx * 8) = v;
}

// ---------------------------------------------------------------------------
__global__ void embed_k(const int* __restrict__ wid, const int* __restrict__ pid,
                        const float* __restrict__ emb1, const float* __restrict__ emb2,
                        f16* __restrict__ X) {
  const int r = blockIdx.x;
  const int d = threadIdx.x;                 // 0..127
  const int wv = wid[r], pv = pid[r];
  X[r * 256 + d]       = (f16)emb1[wv * 128 + d];
  X[r * 256 + 128 + d] = (f16)emb2[pv * 128 + d];
}

// ---------------------------------------------------------------------------
__global__ void make_input(const f16* __restrict__ a, const f16* __restrict__ b,
                           f16* __restrict__ X) {
  const size_t q = ((size_t)blockIdx.x * 256 + threadIdx.x) * 8;
  const f16x8 va = *(const f16x8*)(a + q);
  const f16x8 vb = *(const f16x8*)(b + q);
  *(f16x8*)(X + q) = va + vb;
}

// ---------------------------------------------------------------------------
// gemm_xw: xWp = pack(X[16384][256] @ Wi + bias)  (f16)
// packed store: xWp[row][hcol*4 + q], actual gate col = q*256 + hcol
// ---------------------------------------------------------------------------
__global__ __launch_bounds__(512, 2) void gemm_xw(const f16* __restrict__ X,
                                                  const f16* __restrict__ wipf,
                                                  const float* __restrict__ bias,
                                                  f16* __restrict__ xWp) {
  extern __shared__ char smem[];  // 65536 B : A tile [128][256] f16, swizzled
  const int tid = threadIdx.x, lane = tid & 63, w = tid >> 6;
  const int nb = blockIdx.x, mb = blockIdx.y;
  const char* xbase = (const char*)X + (size_t)mb * 128 * 512;
#pragma unroll
  for (int i = 0; i < 8; ++i) {
    const int row = i * 16 + (tid >> 5);
    const int c16 = tid & 31;
    const uint4 v = *(const uint4*)(xbase + row * 512 + c16 * 16);
    *(uint4*)(smem + row * 512 + ((c16 ^ (row & 7)) << 4)) = v;
  }
  __syncthreads();

  const int mh = w >> 2, nw = w & 3;
  const char* wipf_c = (const char*)wipf;
  const float vb0 = bias[nb * 128 + nw * 32 + (lane & 15)];
  const float vb1 = bias[nb * 128 + nw * 32 + 16 + (lane & 15)];
  f32x4 acc[4][2] = {};
#pragma unroll
  for (int kk = 0; kk < 8; ++kk) {
    const f16x8 b0 = *(const f16x8*)(wipf_c + ((size_t)(kk * 64 + nb * 8 + nw * 2 + 0) << 10) + (lane << 4));
    const f16x8 b1 = *(const f16x8*)(wipf_c + ((size_t)(kk * 64 + nb * 8 + nw * 2 + 1) << 10) + (lane << 4));
#pragma unroll
    for (int m2 = 0; m2 < 4; ++m2) {
      const int row = mh * 64 + m2 * 16 + (lane & 15);
      const f16x8 a = *(const f16x8*)(smem + row * 512 + (((kk * 4 + (lane >> 4)) ^ (row & 7)) << 4));
      acc[m2][0] = __builtin_amdgcn_mfma_f32_16x16x32_f16(a, b0, acc[m2][0], 0, 0, 0);
      acc[m2][1] = __builtin_amdgcn_mfma_f32_16x16x32_f16(a, b1, acc[m2][1], 0, 0, 0);
    }
  }
#pragma unroll
  for (int m2 = 0; m2 < 4; ++m2)
#pragma unroll
    for (int n2 = 0; n2 < 2; ++n2)
#pragma unroll
      for (int j = 0; j < 4; ++j) {
        const int r   = mb * 128 + mh * 64 + m2 * 16 + (lane >> 4) * 4 + j;
        const int col = nb * 128 + nw * 32 + n2 * 16 + (lane & 15);
        xWp[(size_t)r * 1024 + (col & 255) * 4 + (col >> 8)] =
            (f16)(acc[m2][n2][j] + (n2 ? vb1 : vb0));
      }
}

// ---------------------------------------------------------------------------
// lstm_layer: 32 blocks = 4 bg x 8 cq. 512 thr = 8 waves.
// LDS: Wh slice 64KB | hbuf 2x[16][264] f16 | zbuf [16][32][4] f32 | mask[256]
// Wave w -> gate q=w>>1, coltile ct=w&1 (hcols cq*32+ct*16 .. +16).
// Gates: thread tid -> (row=tid>>5, hcol=tid&31), one h value per thread.
// ---------------------------------------------------------------------------
__global__ __launch_bounds__(512, 2) void lstm_layer(
    const f16*  __restrict__ xWp,   // packed [16384][1024] f16 (bias folded)
    const int*  __restrict__ wid,   // [64][256]
    const f16*  __restrict__ whp,   // layer frag slab: (kk*64+nt)*512 + lane*8
    f16* __restrict__ out,          // [64][256][256] f16
    f16* __restrict__ hx,           // [2 slots][32 parts][16][32] f16
    unsigned* __restrict__ flags,   // [32 parts][8 waves]
    int L, int reverse) {
  extern __shared__ char smem[];
  f16*      wh     = (f16*)smem;                      // 65536 B
  f16*      hbuff  = (f16*)(smem + 65536);            // 2*16*264*2 = 16896 B
  float*    zbuf   = (float*)(smem + 82432);          // 16*32*4*4  =  8192 B
  unsigned* mask16 = (unsigned*)(smem + 90624);       // 1024 B
  const int tid  = threadIdx.x;
  const int lane = tid & 63, w = tid >> 6;
  const int bg   = blockIdx.x >> 3, cq = blockIdx.x & 7;
  const int part = blockIdx.x;
  const int r0   = lane & 15, rg = lane >> 4;
  const int q    = w >> 1, ct = w & 1;                // wave's gate / coltile
  const int grow = tid >> 5, ghcol = tid & 31;        // gate-phase mapping
  const int growg = bg * 16 + grow;

  // ---- stage Wh slice -> LDS (64KB, frag-linear [kk*8+w'][lane][16B]) ----
  for (int f = tid; f < 4096; f += 512) {
    const int pr = f >> 6;                            // kk*8 + w'
    const int kk = pr >> 3, wp = pr & 7;
    const int nt = (wp >> 1) * 16 + cq * 2 + (wp & 1);
    const int ln = f & 63;
    *(uint4*)(wh + (size_t)pr * 512 + ln * 8) =
        *(const uint4*)(whp + (size_t)(kk * 64 + nt) * 512 + ln * 8);
  }
  // ---- zero h double-buffer ----
  for (int i = tid; i < 2 * 16 * 264; i += 512) hbuff[i] = (f16)0.f;
  // ---- packed masks: bit j of mask16[t] = (wid[bg*16+j][t] != 0) ----
  if (tid < 256) {
    unsigned m = 0;
#pragma unroll
    for (int j = 0; j < 16; ++j)
      m |= (wid[((bg * 16 + j) << 8) + tid] != 0) ? (1u << j) : 0u;
    mask16[tid] = m;
  }

  float c = 0.f, hprev = 0.f;
  __syncthreads();

#pragma unroll 1
  for (int k = 0; k < 256; ++k) {
    const int t_in = reverse ? (255 - k) : k;
    const int cur = k & 1, nxt = cur ^ 1;

    // 1) xW load for this thread's (row, hcol): 4 gates packed f16x4
    const f16x4 xwv = *(const f16x4*)(xWp + (size_t)((growg << 8) + t_in) * 1024
                                      + (cq * 32 + ghcol) * 4);

    // 2) acquire partner h slices (7 parts x 1KB) into hbuf[cur]
    if (k > 0) {
      const unsigned want = (unsigned)(L * 256 + k);
      if (lane < 56) {
        const int pi = lane >> 3, wv = lane & 7;
        const int cqp = pi + (pi >= cq);
        while (__hip_atomic_load(&flags[(bg * 8 + cqp) * 8 + wv], __ATOMIC_RELAXED,
                                 __HIP_MEMORY_SCOPE_AGENT) < want) {}
      }
      __builtin_amdgcn_fence(__ATOMIC_ACQUIRE, "agent");
      for (int cch = tid; cch < 896; cch += 512) {      // 8B chunks
        const int pi = cch >> 7, i = cch & 127;
        const int cqp = pi + (pi >= cq);
        const int rowp = i >> 3, c4 = i & 7;
        const f16* s = hx + ((size_t)cur * 32 + bg * 8 + cqp) * 512 + rowp * 32 + c4 * 4;
        *(f16x4*)&hbuff[cur * 4224 + rowp * 264 + cqp * 32 + c4 * 4] = *(const f16x4*)s;
      }
    }
    __builtin_amdgcn_sched_barrier(0);
    asm volatile("s_waitcnt lgkmcnt(0)\n\ts_barrier" ::: "memory");
    __builtin_amdgcn_sched_barrier(0);

    // 3) z(our 8 n-tiles worth, 1 per wave) = H_k @ Wh_slice : 8 MFMA/wave
    f32x4 acc = {};
#pragma unroll
    for (int kk = 0; kk < 8; ++kk) {
      const f16x8 a = *(const f16x8*)&hbuff[cur * 4224 + r0 * 264 + kk * 32 + rg * 8];
      const f16x8 b = *(const f16x8*)(wh + ((kk * 8 + w) << 9) + lane * 8);
      acc = __builtin_amdgcn_mfma_f32_16x16x32_f16(a, b, acc, 0, 0, 0);
    }
    // z transpose via LDS: zbuf[row][hcol][q]
#pragma unroll
    for (int j = 0; j < 4; ++j)
      zbuf[((rg * 4 + j) * 32 + ct * 16 + r0) * 4 + q] = acc[j];

    __builtin_amdgcn_sched_barrier(0);
    asm volatile("s_waitcnt lgkmcnt(0)\n\ts_barrier" ::: "memory");
    __builtin_amdgcn_sched_barrier(0);

    // 4) gates: one (row, hcol) per thread
    const f32x4 z = *(const f32x4*)&zbuf[(grow * 32 + ghcol) * 4];
    const float zi = z[0] + (float)xwv[0];
    const float zf = z[1] + (float)xwv[1];
    const float zc = z[2] + (float)xwv[2];
    const float zo = z[3] + (float)xwv[3];
    const float ig = fast_sigmoid(zi);
    const float fg = fast_sigmoid(zf);
    const float og = fast_sigmoid(zo);
    const float cb = fast_tanh(zc);
    const float cn = fg * c + ig * cb;
    const float hn = og * fast_tanh(cn);
    const bool  m  = ((mask16[t_in] >> grow) & 1u) != 0u;
    c     = m ? cn : c;
    hprev = m ? hn : hprev;
    const f16 hv = (f16)hprev;

    // 5) publish: hbuf[nxt] own cols, hx slot, out; per-wave release flag
    hbuff[nxt * 4224 + grow * 264 + cq * 32 + ghcol] = hv;
    hx[((size_t)nxt * 32 + part) * 512 + grow * 32 + ghcol] = hv;
    out[((size_t)(growg << 8) + k) * 256 + cq * 32 + ghcol] = hv;
    if (lane == 0)
      __hip_atomic_store(&flags[part * 8 + w], (unsigned)(L * 256 + k + 1),
                         __ATOMIC_RELEASE, __HIP_MEMORY_SCOPE_AGENT);
    // (no end barrier: next step's post-copy barrier orders hbuf[nxt]/zbuf)
  }
}

// ---------------------------------------------------------------------------
// final: softmax((o6+o7) @ Wd + bd) -> f32 out [16384][128]   (o* are f16)
// ---------------------------------------------------------------------------
__global__ __launch_bounds__(512, 2) void final_k(const f16* __restrict__ o0,
                                                  const f16* __restrict__ o1,
                                                  const f16* __restrict__ wdpf,
                                                  const float* __restrict__ bd,
                                                  float* __restrict__ outp) {
  const int tid = threadIdx.x, lane = tid & 63, w = tid >> 6;
  const int rbase = blockIdx.x * 128 + w * 16;
  const char* wdpf_c = (const char*)wdpf;

  f32x4 acc[8] = {};
#pragma unroll
  for (int kk = 0; kk < 8; ++kk) {
    const int r  = rbase + (lane & 15);
    const int k0 = kk * 32 + (lane >> 4) * 8;
    const f16x8 x = *(const f16x8*)(o0 + (size_t)r * 256 + k0);
    const f16x8 y = *(const f16x8*)(o1 + (size_t)r * 256 + k0);
    const f16x8 a = x + y;
#pragma unroll
    for (int nt = 0; nt < 8; ++nt) {
      const f16x8 b = *(const f16x8*)(wdpf_c + ((size_t)(kk * 8 + nt) << 10) + (lane << 4));
      acc[nt] = __builtin_amdgcn_mfma_f32_16x16x32_f16(a, b, acc[nt], 0, 0, 0);
    }
  }

  float vb[8];
#pragma unroll
  for (int nt = 0; nt < 8; ++nt) vb[nt] = bd[nt * 16 + (lane & 15)];

#pragma unroll
  for (int j = 0; j < 4; ++j) {
    float v[8];
#pragma unroll
    for (int nt = 0; nt < 8; ++nt) v[nt] = acc[nt][j] + vb[nt];
    float mx = v[0];
#pragma unroll
    for (int nt = 1; nt < 8; ++nt) mx = fmaxf(mx, v[nt]);
#pragma unroll
    for (int m = 1; m < 16; m <<= 1) mx = fmaxf(mx, __shfl_xor(mx, m, 64));
    float s = 0.f;
#pragma unroll
    for (int nt = 0; nt < 8; ++nt) {
      v[nt] = __builtin_amdgcn_exp2f(1.44269504f * (v[nt] - mx));
      s += v[nt];
    }
#pragma unroll
    for (int m = 1; m < 16; m <<= 1) s += __shfl_xor(s, m, 64);
    const float rs = __builtin_amdgcn_rcpf(s);
    const int r = rbase + (lane >> 4) * 4 + j;
#pragma unroll
    for (int nt = 0; nt < 8; ++nt)
      outp[(size_t)r * 128 + nt * 16 + (lane & 15)] = v[nt] * rs;
  }
}

// ---------------------------------------------------------------------------
extern "C" void kernel_launch(void* const* d_in, const int* in_sizes, int n_in,
                              void* d_out, int out_size, void* d_ws, size_t ws_size,
                              hipStream_t stream) {
  const int*   wid  = (const int*)d_in[0];
  const int*   pid  = (const int*)d_in[1];
  const float* emb1 = (const float*)d_in[2];
  const float* emb2 = (const float*)d_in[3];
  const float* Wis  = (const float*)d_in[4];
  const float* Whs  = (const float*)d_in[5];
  const float* bs   = (const float*)d_in[6];
  const float* Wd   = (const float*)d_in[7];
  const float* bd   = (const float*)d_in[8];

  char* ws = (char*)d_ws;
  f16*      Whp   = (f16*)(ws + 0);             //  4,194,304
  f16*      Wipf  = (f16*)(ws + 4194304);       //  4,194,304
  f16*      Wdpf  = (f16*)(ws + 8388608);       //     65,536
  f16*      X     = (f16*)(ws + 8454144);       //  8,388,608
  f16*      xWp   = (f16*)(ws + 16842752);      // 33,554,432
  f16*      o0    = (f16*)(ws + 50397184);      //  8,388,608
  f16*      o1    = (f16*)(ws + 58785792);      //  8,388,608
  f16*      hx    = (f16*)(ws + 67174400);      //     65,536
  unsigned* flags = (unsigned*)(ws + 67239936); //      1,024

  hipFuncSetAttribute((const void*)gemm_xw,    hipFuncAttributeMaxDynamicSharedMemorySize, 65536);
  hipFuncSetAttribute((const void*)lstm_layer, hipFuncAttributeMaxDynamicSharedMemorySize, 91648);
  hipMemsetAsync(flags, 0, 1024, stream);

  pack_frags<<<1024, 256, 0, stream>>>(Whs, Whp, 64);
  pack_frags<<<1024, 256, 0, stream>>>(Wis, Wipf, 64);
  pack_frags<<<16,   256, 0, stream>>>(Wd,  Wdpf, 8);
  embed_k<<<16384, 128, 0, stream>>>(wid, pid, emb1, emb2, X);

  f16* obuf[2] = {o0, o1};
  for (int L = 0; L < 8; ++L) {
    const f16* xin = X;
    if (L == 1) {
      xin = o0;                                   // identity input, same layout
    } else if (L >= 2) {
      make_input<<<2048, 256, 0, stream>>>(obuf[L & 1], obuf[(L - 1) & 1], X);
    }
    gemm_xw<<<dim3(8, 128), 512, 65536, stream>>>(xin, Wipf + (size_t)L * 262144,
                                                  bs + L * 1024, xWp);
    lstm_layer<<<32, 512, 91648, stream>>>(xWp, wid, Whp + (size_t)L * 262144,
                                           obuf[L & 1], hx, flags, L, L & 1);
  }
  final_k<<<128, 512, 0, stream>>>(o0, o1, Wdpf, bd, (float*)d_out);
}

// Round 8
// 12123.286 us; speedup vs baseline: 2.0723x; 2.0723x over previous
//
#include <hip/hip_runtime.h>

// ============================================================================
// 8-layer alternating-direction masked LSTM stack + embed + dense/softmax.
// R8 = R2 skeleton (4 blocks x 16 rows, 512 thr, Wh split REG(AGPR-parked)
// kk0-3 / LDS kk4-5 / L2-stream kk6-7, one lgkm barrier/step) + proven
// latency killers:
//  (1) xWp packed f16x4 (i,f,c,o per h-col) + ONE-STEP-AHEAD prefetch
//      -> gates consume loads issued a full step earlier (no HBM stall,
//         8x8B loads instead of 32x2B),
//  (2) masks packed per-t in LDS (1 ds_read/step instead of 4 global loads),
//  (3) out stored f16 (half write traffic), final_k consumes f16,
//  (4) kk6-7 stream issued at step top (L2 latency hides under reg MFMAs).
// ============================================================================

typedef _Float16 f16;
typedef _Float16 f16x8 __attribute__((ext_vector_type(8)));
typedef _Float16 f16x4 __attribute__((ext_vector_type(4)));
typedef float    f32x4 __attribute__((ext_vector_type(4)));

#define DEVI static __device__ __forceinline__

DEVI float fast_sigmoid(float x) {
  return __builtin_amdgcn_rcpf(1.f + __builtin_amdgcn_exp2f(-1.44269504f * x));
}
DEVI float fast_tanh(float x) {
  return 1.f - 2.f * __builtin_amdgcn_rcpf(1.f + __builtin_amdgcn_exp2f(2.88539008f * x));
}
// wave w owns coltiles {2w, 2w+1}; its 8 ntiles: quadrant q=j2>>1 (i,f,c,o),
// parity p=j2&1:  ntg = q*16 + 2w + p
DEVI int ntg_of(int w, int j2) { return ((j2 >> 1) << 4) + 2 * w + (j2 & 1); }

// ---------------------------------------------------------------------------
// pack_frags: dst frag layout [L][kk][nt][lane][8 f16].
// B-frag (16x16x32): lane l holds B[k=kk*32+(l>>4)*8+e][col=nt*16+(l&15)]
// ---------------------------------------------------------------------------
__global__ void pack_frags(const float* __restrict__ src, f16* __restrict__ dst, int nct) {
  const int idx  = blockIdx.x * 256 + threadIdx.x;
  const int lane = idx & 63;
  const int f    = idx >> 6;
  const int nt   = f % nct;
  const int g2   = f / nct;
  const int kk   = g2 & 7;
  const int L    = g2 >> 3;
  const int ncols = nct * 16;
  const float* s = src + (size_t)(L * 256 + kk * 32 + (lane >> 4) * 8) * ncols + nt * 16 + (lane & 15);
  f16x8 v;
#pragma unroll
  for (int e = 0; e < 8; ++e) v[e] = (f16)s[(size_t)e * ncols];
  *(f16x8*)(dst + (size_t)idx * 8) = v;
}

// ---------------------------------------------------------------------------
__global__ void embed_k(const int* __restrict__ wid, const int* __restrict__ pid,
                        const float* __restrict__ emb1, const float* __restrict__ emb2,
                        f16* __restrict__ X) {
  const int r = blockIdx.x;
  const int d = threadIdx.x;                 // 0..127
  const int wv = wid[r], pv = pid[r];
  X[r * 256 + d]       = (f16)emb1[wv * 128 + d];
  X[r * 256 + 128 + d] = (f16)emb2[pv * 128 + d];
}

// ---------------------------------------------------------------------------
__global__ void make_input(const f16* __restrict__ a, const f16* __restrict__ b,
                           f16* __restrict__ X) {
  const size_t q = ((size_t)blockIdx.x * 256 + threadIdx.x) * 8;
  const f16x8 va = *(const f16x8*)(a + q);
  const f16x8 vb = *(const f16x8*)(b + q);
  *(f16x8*)(X + q) = va + vb;
}

// ---------------------------------------------------------------------------
// gemm_xw: xWp = pack(X[16384][256] @ Wi + bias)  (f16)
// packed store: xWp[row][hcol*4 + q], actual gate col = q*256 + hcol
// ---------------------------------------------------------------------------
__global__ __launch_bounds__(512, 2) void gemm_xw(const f16* __restrict__ X,
                                                  const f16* __restrict__ wipf,
                                                  const float* __restrict__ bias,
                                                  f16* __restrict__ xWp) {
  extern __shared__ char smem[];  // 65536 B : A tile [128][256] f16, swizzled
  const int tid = threadIdx.x, lane = tid & 63, w = tid >> 6;
  const int nb = blockIdx.x, mb = blockIdx.y;
  const char* xbase = (const char*)X + (size_t)mb * 128 * 512;
#pragma unroll
  for (int i = 0; i < 8; ++i) {
    const int row = i * 16 + (tid >> 5);
    const int c16 = tid & 31;
    const uint4 v = *(const uint4*)(xbase + row * 512 + c16 * 16);
    *(uint4*)(smem + row * 512 + ((c16 ^ (row & 7)) << 4)) = v;
  }
  __syncthreads();

  const int mh = w >> 2, nw = w & 3;
  const char* wipf_c = (const char*)wipf;
  const float vb0 = bias[nb * 128 + nw * 32 + (lane & 15)];
  const float vb1 = bias[nb * 128 + nw * 32 + 16 + (lane & 15)];
  f32x4 acc[4][2] = {};
#pragma unroll
  for (int kk = 0; kk < 8; ++kk) {
    const f16x8 b0 = *(const f16x8*)(wipf_c + ((size_t)(kk * 64 + nb * 8 + nw * 2 + 0) << 10) + (lane << 4));
    const f16x8 b1 = *(const f16x8*)(wipf_c + ((size_t)(kk * 64 + nb * 8 + nw * 2 + 1) << 10) + (lane << 4));
#pragma unroll
    for (int m2 = 0; m2 < 4; ++m2) {
      const int row = mh * 64 + m2 * 16 + (lane & 15);
      const f16x8 a = *(const f16x8*)(smem + row * 512 + (((kk * 4 + (lane >> 4)) ^ (row & 7)) << 4));
      acc[m2][0] = __builtin_amdgcn_mfma_f32_16x16x32_f16(a, b0, acc[m2][0], 0, 0, 0);
      acc[m2][1] = __builtin_amdgcn_mfma_f32_16x16x32_f16(a, b1, acc[m2][1], 0, 0, 0);
    }
  }
#pragma unroll
  for (int m2 = 0; m2 < 4; ++m2)
#pragma unroll
    for (int n2 = 0; n2 < 2; ++n2)
#pragma unroll
      for (int j = 0; j < 4; ++j) {
        const int r   = mb * 128 + mh * 64 + m2 * 16 + (lane >> 4) * 4 + j;
        const int col = nb * 128 + nw * 32 + n2 * 16 + (lane & 15);
        xWp[(size_t)r * 1024 + (col & 255) * 4 + (col >> 8)] =
            (f16)(acc[m2][n2][j] + (n2 ? vb1 : vb0));
      }
}

// ---------------------------------------------------------------------------
// lstm_layer: 4 blocks x 16 batch rows, full 256 h-cols, 512 thr (8 waves).
// Wh: kk0-3 reg/AGPR-parked, kk4-5 LDS, kk6-7 L2-streamed per step.
// xW prefetched one step ahead (packed f16x4). Masks packed in LDS.
// One lgkm-only barrier per step; h double-buffered in LDS; out f16.
// ---------------------------------------------------------------------------
__global__ __launch_bounds__(512, 2) void lstm_layer(
    const f16*  __restrict__ xWp,   // packed [16384][1024] f16 (bias folded)
    const int*  __restrict__ wid,   // [64][256]
    const f16*  __restrict__ whp,   // layer frag slab: (kk*64+nt)*512 + lane*8
    f16* __restrict__ out,          // [64][256][256] f16
    int reverse) {
  extern __shared__ char smem[];               // 131072 wh(kk4,5) + 16896 hbuf + 1024 mask
  f16*      hbuf   = (f16*)(smem + 131072);    // 2 x [16][264] f16
  unsigned* mask16 = (unsigned*)(smem + 147968);
  const int tid  = threadIdx.x;
  const int lane = tid & 63, w = tid >> 6;
  const int g    = blockIdx.x;
  const int r0   = lane & 15, rg = lane >> 4;
  const int ct0  = 2 * w;
  const char* whp_c = (const char*)whp;

  // stage Wh kk4,kk5 -> LDS (frag layout is load-linear, conflict-free)
  {
    const char* src = whp_c + (4 << 16);
#pragma unroll
    for (int i = 0; i < 16; ++i) {
      const int off = i * 8192 + tid * 16;
      *(uint4*)(smem + off) = *(const uint4*)(src + off);
    }
  }
  for (int i = tid; i < 2 * 16 * 264; i += 512) hbuf[i] = (f16)0.f;
  // packed masks: bit j of mask16[t] = (wid[g*16+j][t] != 0)
  if (tid < 256) {
    unsigned m = 0;
#pragma unroll
    for (int j = 0; j < 16; ++j)
      m |= (wid[((g * 16 + j) << 8) + tid] != 0) ? (1u << j) : 0u;
    mask16[tid] = m;
  }

  // persistent Wh kk0..3 (32 frags = 128 regs; compiler parks in AGPRs)
  f16x8 regB[32];
#pragma unroll
  for (int kk = 0; kk < 4; ++kk)
#pragma unroll
    for (int j2 = 0; j2 < 8; ++j2)
      regB[kk * 8 + j2] = *(const f16x8*)(whp_c + ((size_t)(kk * 64 + ntg_of(w, j2)) << 10) + (lane << 4));

  float c[8], hreg[8];
#pragma unroll
  for (int i = 0; i < 8; ++i) { c[i] = 0.f; hreg[i] = 0.f; }

  // preload xW for step 0: 8 x f16x4 (p in {0,1}, j in 0..3)
  const int t0 = reverse ? 255 : 0;
  f16x4 xwc[2][4];
#pragma unroll
  for (int p = 0; p < 2; ++p)
#pragma unroll
    for (int j = 0; j < 4; ++j)
      xwc[p][j] = *(const f16x4*)(xWp + (size_t)(((g * 16 + rg * 4 + j) << 8) + t0) * 1024
                                  + ((ct0 + p) * 16 + r0) * 4);

  __syncthreads();

#pragma unroll 1
  for (int k = 0; k < 256; ++k) {
    const int t_in = reverse ? (255 - k) : k;
    const f16* hc = hbuf + (k & 1) * 4224;
    f16*       hn = hbuf + ((k & 1) ^ 1) * 4224;

    // 1) issue kk6,kk7 stream loads NOW (consumed after kk0-5 MFMAs -> L2
    //    latency hidden under compute)
    f16x8 sb6[8], sb7[8];
#pragma unroll
    for (int j2 = 0; j2 < 8; ++j2)
      sb6[j2] = *(const f16x8*)(whp_c + ((size_t)(6 * 64 + ntg_of(w, j2)) << 10) + (lane << 4));
#pragma unroll
    for (int j2 = 0; j2 < 8; ++j2)
      sb7[j2] = *(const f16x8*)(whp_c + ((size_t)(7 * 64 + ntg_of(w, j2)) << 10) + (lane << 4));

    // 2) MFMA kk0-3 (REG/AGPR)
    f32x4 acc[8] = {};
#pragma unroll
    for (int kk = 0; kk < 4; ++kk) {
      const f16x8 a = *(const f16x8*)&hc[r0 * 264 + kk * 32 + rg * 8];
#pragma unroll
      for (int j2 = 0; j2 < 8; ++j2)
        acc[j2] = __builtin_amdgcn_mfma_f32_16x16x32_f16(a, regB[kk * 8 + j2], acc[j2], 0, 0, 0);
    }

    // 3) MFMA kk4-5 (LDS)
#pragma unroll
    for (int kk = 4; kk < 6; ++kk) {
      const f16x8 a = *(const f16x8*)&hc[r0 * 264 + kk * 32 + rg * 8];
#pragma unroll
      for (int j2 = 0; j2 < 8; ++j2) {
        const f16x8 b8 = *(const f16x8*)(smem + ((size_t)((kk - 4) * 64 + ntg_of(w, j2)) << 10) + (lane << 4));
        acc[j2] = __builtin_amdgcn_mfma_f32_16x16x32_f16(a, b8, acc[j2], 0, 0, 0);
      }
    }

    // 4) MFMA kk6, kk7 (streamed)
    {
      const f16x8 a6 = *(const f16x8*)&hc[r0 * 264 + 6 * 32 + rg * 8];
#pragma unroll
      for (int j2 = 0; j2 < 8; ++j2)
        acc[j2] = __builtin_amdgcn_mfma_f32_16x16x32_f16(a6, sb6[j2], acc[j2], 0, 0, 0);
      const f16x8 a7 = *(const f16x8*)&hc[r0 * 264 + 7 * 32 + rg * 8];
#pragma unroll
      for (int j2 = 0; j2 < 8; ++j2)
        acc[j2] = __builtin_amdgcn_mfma_f32_16x16x32_f16(a7, sb7[j2], acc[j2], 0, 0, 0);
    }

    // 5) prefetch next step's xW (consumed NEXT step -> full-step slack)
    const int tn = (k < 255) ? (reverse ? 254 - k : k + 1) : t0;
    f16x4 xwn[2][4];
#pragma unroll
    for (int p = 0; p < 2; ++p)
#pragma unroll
      for (int j = 0; j < 4; ++j)
        xwn[p][j] = *(const f16x4*)(xWp + (size_t)(((g * 16 + rg * 4 + j) << 8) + tn) * 1024
                                    + ((ct0 + p) * 16 + r0) * 4);

    // 6) gates (f32) with mask bits from LDS; state update
    const unsigned mw = mask16[t_in];
#pragma unroll
    for (int p = 0; p < 2; ++p) {
#pragma unroll
      for (int j = 0; j < 4; ++j) {
        const int idx = p * 4 + j;
        const float zi = acc[0 + p][j] + (float)xwc[p][j][0];
        const float zf = acc[2 + p][j] + (float)xwc[p][j][1];
        const float zc = acc[4 + p][j] + (float)xwc[p][j][2];
        const float zo = acc[6 + p][j] + (float)xwc[p][j][3];
        const float ig = fast_sigmoid(zi);
        const float fg = fast_sigmoid(zf);
        const float og = fast_sigmoid(zo);
        const float cb = fast_tanh(zc);
        const float cn = fg * c[idx] + ig * cb;
        const float hv_ = og * fast_tanh(cn);
        const bool  m  = ((mw >> (rg * 4 + j)) & 1u) != 0u;
        c[idx]    = m ? cn : c[idx];
        hreg[idx] = m ? hv_ : hreg[idx];
      }
    }

    // 7) publish H_{k+1} (LDS) + out store (f16, fire-and-forget)
#pragma unroll
    for (int p = 0; p < 2; ++p)
#pragma unroll
      for (int j = 0; j < 4; ++j) {
        const f16 hv = (f16)hreg[p * 4 + j];
        hn[(rg * 4 + j) * 264 + (ct0 + p) * 16 + r0] = hv;
        out[((size_t)((g * 16 + rg * 4 + j) << 8) + k) * 256 + (ct0 + p) * 16 + r0] = hv;
      }

    // 8) one lgkm-only barrier (vmcnt stays in flight across it)
    __builtin_amdgcn_sched_barrier(0);
    asm volatile("s_waitcnt lgkmcnt(0)\n\ts_barrier" ::: "memory");
    __builtin_amdgcn_sched_barrier(0);

    // 9) rotate prefetched xW
#pragma unroll
    for (int p = 0; p < 2; ++p)
#pragma unroll
      for (int j = 0; j < 4; ++j) xwc[p][j] = xwn[p][j];
  }
}

// ---------------------------------------------------------------------------
// final: softmax((o6+o7) @ Wd + bd) -> f32 out [16384][128]   (o* are f16)
// ---------------------------------------------------------------------------
__global__ __launch_bounds__(512, 2) void final_k(const f16* __restrict__ o0,
                                                  const f16* __restrict__ o1,
                                                  const f16* __restrict__ wdpf,
                                                  const float* __restrict__ bd,
                                                  float* __restrict__ outp) {
  const int tid = threadIdx.x, lane = tid & 63, w = tid >> 6;
  const int rbase = blockIdx.x * 128 + w * 16;
  const char* wdpf_c = (const char*)wdpf;

  f32x4 acc[8] = {};
#pragma unroll
  for (int kk = 0; kk < 8; ++kk) {
    const int r  = rbase + (lane & 15);
    const int k0 = kk * 32 + (lane >> 4) * 8;
    const f16x8 x = *(const f16x8*)(o0 + (size_t)r * 256 + k0);
    const f16x8 y = *(const f16x8*)(o1 + (size_t)r * 256 + k0);
    const f16x8 a = x + y;
#pragma unroll
    for (int nt = 0; nt < 8; ++nt) {
      const f16x8 b = *(const f16x8*)(wdpf_c + ((size_t)(kk * 8 + nt) << 10) + (lane << 4));
      acc[nt] = __builtin_amdgcn_mfma_f32_16x16x32_f16(a, b, acc[nt], 0, 0, 0);
    }
  }

  float vb[8];
#pragma unroll
  for (int nt = 0; nt < 8; ++nt) vb[nt] = bd[nt * 16 + (lane & 15)];

#pragma unroll
  for (int j = 0; j < 4; ++j) {
    float v[8];
#pragma unroll
    for (int nt = 0; nt < 8; ++nt) v[nt] = acc[nt][j] + vb[nt];
    float mx = v[0];
#pragma unroll
    for (int nt = 1; nt < 8; ++nt) mx = fmaxf(mx, v[nt]);
#pragma unroll
    for (int m = 1; m < 16; m <<= 1) mx = fmaxf(mx, __shfl_xor(mx, m, 64));
    float s = 0.f;
#pragma unroll
    for (int nt = 0; nt < 8; ++nt) {
      v[nt] = __builtin_amdgcn_exp2f(1.44269504f * (v[nt] - mx));
      s += v[nt];
    }
#pragma unroll
    for (int m = 1; m < 16; m <<= 1) s += __shfl_xor(s, m, 64);
    const float rs = __builtin_amdgcn_rcpf(s);
    const int r = rbase + (lane >> 4) * 4 + j;
#pragma unroll
    for (int nt = 0; nt < 8; ++nt)
      outp[(size_t)r * 128 + nt * 16 + (lane & 15)] = v[nt] * rs;
  }
}

// ---------------------------------------------------------------------------
extern "C" void kernel_launch(void* const* d_in, const int* in_sizes, int n_in,
                              void* d_out, int out_size, void* d_ws, size_t ws_size,
                              hipStream_t stream) {
  const int*   wid  = (const int*)d_in[0];
  const int*   pid  = (const int*)d_in[1];
  const float* emb1 = (const float*)d_in[2];
  const float* emb2 = (const float*)d_in[3];
  const float* Wis  = (const float*)d_in[4];
  const float* Whs  = (const float*)d_in[5];
  const float* bs   = (const float*)d_in[6];
  const float* Wd   = (const float*)d_in[7];
  const float* bd   = (const float*)d_in[8];

  char* ws = (char*)d_ws;
  f16* Whp  = (f16*)(ws + 0);          //  4,194,304
  f16* Wipf = (f16*)(ws + 4194304);    //  4,194,304
  f16* Wdpf = (f16*)(ws + 8388608);    //     65,536
  f16* X    = (f16*)(ws + 8454144);    //  8,388,608
  f16* xWp  = (f16*)(ws + 16842752);   // 33,554,432
  f16* o0   = (f16*)(ws + 50397184);   //  8,388,608
  f16* o1   = (f16*)(ws + 58785792);   //  8,388,608

  hipFuncSetAttribute((const void*)gemm_xw,    hipFuncAttributeMaxDynamicSharedMemorySize, 65536);
  hipFuncSetAttribute((const void*)lstm_layer, hipFuncAttributeMaxDynamicSharedMemorySize, 148992);

  pack_frags<<<1024, 256, 0, stream>>>(Whs, Whp, 64);
  pack_frags<<<1024, 256, 0, stream>>>(Wis, Wipf, 64);
  pack_frags<<<16,   256, 0, stream>>>(Wd,  Wdpf, 8);
  embed_k<<<16384, 128, 0, stream>>>(wid, pid, emb1, emb2, X);

  f16* obuf[2] = {o0, o1};
  for (int L = 0; L < 8; ++L) {
    const f16* xin = X;
    if (L == 1) {
      xin = o0;                                   // identity input, same layout
    } else if (L >= 2) {
      make_input<<<2048, 256, 0, stream>>>(obuf[L & 1], obuf[(L - 1) & 1], X);
    }
    gemm_xw<<<dim3(8, 128), 512, 65536, stream>>>(xin, Wipf + (size_t)L * 262144,
                                                  bs + L * 1024, xWp);
    lstm_layer<<<4, 512, 148992, stream>>>(xWp, wid, Whp + (size_t)L * 262144,
                                           obuf[L & 1], L & 1);
  }
  final_k<<<128, 512, 0, stream>>>(o0, o1, Wdpf, bd, (float*)d_out);
}

// Round 9
// 10468.024 us; speedup vs baseline: 2.4000x; 1.1581x over previous
//
#include <hip/hip_runtime.h>

// ============================================================================
// 8-layer alternating-direction masked LSTM stack + embed + dense/softmax.
// R9 = R8 skeleton (4 blocks x 16 rows, 512 thr, Wh split kk0-3 REG(AGPR) /
// kk4-5 LDS / kk6-7 L2-stream, packed xWp, masks in LDS, f16 out, one
// lgkm-only barrier/step) with ONE change:
//   kk6-7 stream loads are issued ONE FULL STEP AHEAD (right after the
//   current values are consumed by the kk6-7 MFMAs), so the ~2000cy L2
//   serialization hides under gates+publish+barrier+kk0-5 (~3500cy slack).
//   WAR reuse of the same 32 landing VGPRs; lgkm-only barrier keeps the
//   loads in flight across the step boundary. xW reverted to in-step loads
//   (R8 measured its prefetch at exactly 0; frees 16 VGPRs for this).
// ============================================================================

typedef _Float16 f16;
typedef _Float16 f16x8 __attribute__((ext_vector_type(8)));
typedef _Float16 f16x4 __attribute__((ext_vector_type(4)));
typedef float    f32x4 __attribute__((ext_vector_type(4)));

#define DEVI static __device__ __forceinline__

DEVI float fast_sigmoid(float x) {
  return __builtin_amdgcn_rcpf(1.f + __builtin_amdgcn_exp2f(-1.44269504f * x));
}
DEVI float fast_tanh(float x) {
  return 1.f - 2.f * __builtin_amdgcn_rcpf(1.f + __builtin_amdgcn_exp2f(2.88539008f * x));
}
// wave w owns coltiles {2w, 2w+1}; its 8 ntiles: quadrant q=j2>>1 (i,f,c,o),
// parity p=j2&1:  ntg = q*16 + 2w + p
DEVI int ntg_of(int w, int j2) { return ((j2 >> 1) << 4) + 2 * w + (j2 & 1); }

// ---------------------------------------------------------------------------
// pack_frags: dst frag layout [L][kk][nt][lane][8 f16].
// B-frag (16x16x32): lane l holds B[k=kk*32+(l>>4)*8+e][col=nt*16+(l&15)]
// ---------------------------------------------------------------------------
__global__ void pack_frags(const float* __restrict__ src, f16* __restrict__ dst, int nct) {
  const int idx  = blockIdx.x * 256 + threadIdx.x;
  const int lane = idx & 63;
  const int f    = idx >> 6;
  const int nt   = f % nct;
  const int g2   = f / nct;
  const int kk   = g2 & 7;
  const int L    = g2 >> 3;
  const int ncols = nct * 16;
  const float* s = src + (size_t)(L * 256 + kk * 32 + (lane >> 4) * 8) * ncols + nt * 16 + (lane & 15);
  f16x8 v;
#pragma unroll
  for (int e = 0; e < 8; ++e) v[e] = (f16)s[(size_t)e * ncols];
  *(f16x8*)(dst + (size_t)idx * 8) = v;
}

// ---------------------------------------------------------------------------
__global__ void embed_k(const int* __restrict__ wid, const int* __restrict__ pid,
                        const float* __restrict__ emb1, const float* __restrict__ emb2,
                        f16* __restrict__ X) {
  const int r = blockIdx.x;
  const int d = threadIdx.x;                 // 0..127
  const int wv = wid[r], pv = pid[r];
  X[r * 256 + d]       = (f16)emb1[wv * 128 + d];
  X[r * 256 + 128 + d] = (f16)emb2[pv * 128 + d];
}

// ---------------------------------------------------------------------------
__global__ void make_input(const f16* __restrict__ a, const f16* __restrict__ b,
                           f16* __restrict__ X) {
  const size_t q = ((size_t)blockIdx.x * 256 + threadIdx.x) * 8;
  const f16x8 va = *(const f16x8*)(a + q);
  const f16x8 vb = *(const f16x8*)(b + q);
  *(f16x8*)(X + q) = va + vb;
}

// ---------------------------------------------------------------------------
// gemm_xw: xWp = pack(X[16384][256] @ Wi + bias)  (f16)
// packed store: xWp[row][hcol*4 + q], actual gate col = q*256 + hcol
// ---------------------------------------------------------------------------
__global__ __launch_bounds__(512, 2) void gemm_xw(const f16* __restrict__ X,
                                                  const f16* __restrict__ wipf,
                                                  const float* __restrict__ bias,
                                                  f16* __restrict__ xWp) {
  extern __shared__ char smem[];  // 65536 B : A tile [128][256] f16, swizzled
  const int tid = threadIdx.x, lane = tid & 63, w = tid >> 6;
  const int nb = blockIdx.x, mb = blockIdx.y;
  const char* xbase = (const char*)X + (size_t)mb * 128 * 512;
#pragma unroll
  for (int i = 0; i < 8; ++i) {
    const int row = i * 16 + (tid >> 5);
    const int c16 = tid & 31;
    const uint4 v = *(const uint4*)(xbase + row * 512 + c16 * 16);
    *(uint4*)(smem + row * 512 + ((c16 ^ (row & 7)) << 4)) = v;
  }
  __syncthreads();

  const int mh = w >> 2, nw = w & 3;
  const char* wipf_c = (const char*)wipf;
  const float vb0 = bias[nb * 128 + nw * 32 + (lane & 15)];
  const float vb1 = bias[nb * 128 + nw * 32 + 16 + (lane & 15)];
  f32x4 acc[4][2] = {};
#pragma unroll
  for (int kk = 0; kk < 8; ++kk) {
    const f16x8 b0 = *(const f16x8*)(wipf_c + ((size_t)(kk * 64 + nb * 8 + nw * 2 + 0) << 10) + (lane << 4));
    const f16x8 b1 = *(const f16x8*)(wipf_c + ((size_t)(kk * 64 + nb * 8 + nw * 2 + 1) << 10) + (lane << 4));
#pragma unroll
    for (int m2 = 0; m2 < 4; ++m2) {
      const int row = mh * 64 + m2 * 16 + (lane & 15);
      const f16x8 a = *(const f16x8*)(smem + row * 512 + (((kk * 4 + (lane >> 4)) ^ (row & 7)) << 4));
      acc[m2][0] = __builtin_amdgcn_mfma_f32_16x16x32_f16(a, b0, acc[m2][0], 0, 0, 0);
      acc[m2][1] = __builtin_amdgcn_mfma_f32_16x16x32_f16(a, b1, acc[m2][1], 0, 0, 0);
    }
  }
#pragma unroll
  for (int m2 = 0; m2 < 4; ++m2)
#pragma unroll
    for (int n2 = 0; n2 < 2; ++n2)
#pragma unroll
      for (int j = 0; j < 4; ++j) {
        const int r   = mb * 128 + mh * 64 + m2 * 16 + (lane >> 4) * 4 + j;
        const int col = nb * 128 + nw * 32 + n2 * 16 + (lane & 15);
        xWp[(size_t)r * 1024 + (col & 255) * 4 + (col >> 8)] =
            (f16)(acc[m2][n2][j] + (n2 ? vb1 : vb0));
      }
}

// ---------------------------------------------------------------------------
// lstm_layer: 4 blocks x 16 batch rows, full 256 h-cols, 512 thr (8 waves).
// Wh: kk0-3 reg/AGPR-parked, kk4-5 LDS, kk6-7 streamed ONE STEP AHEAD.
// ---------------------------------------------------------------------------
__global__ __launch_bounds__(512, 2) void lstm_layer(
    const f16*  __restrict__ xWp,   // packed [16384][1024] f16 (bias folded)
    const int*  __restrict__ wid,   // [64][256]
    const f16*  __restrict__ whp,   // layer frag slab: (kk*64+nt)*512 + lane*8
    f16* __restrict__ out,          // [64][256][256] f16
    int reverse) {
  extern __shared__ char smem[];               // 131072 wh(kk4,5) + 16896 hbuf + 1024 mask
  f16*      hbuf   = (f16*)(smem + 131072);    // 2 x [16][264] f16
  unsigned* mask16 = (unsigned*)(smem + 147968);
  const int tid  = threadIdx.x;
  const int lane = tid & 63, w = tid >> 6;
  const int g    = blockIdx.x;
  const int r0   = lane & 15, rg = lane >> 4;
  const int ct0  = 2 * w;
  const char* whp_c = (const char*)whp;

  // stage Wh kk4,kk5 -> LDS (frag layout is load-linear, conflict-free)
  {
    const char* src = whp_c + (4 << 16);
#pragma unroll
    for (int i = 0; i < 16; ++i) {
      const int off = i * 8192 + tid * 16;
      *(uint4*)(smem + off) = *(const uint4*)(src + off);
    }
  }
  for (int i = tid; i < 2 * 16 * 264; i += 512) hbuf[i] = (f16)0.f;
  // packed masks: bit j of mask16[t] = (wid[g*16+j][t] != 0)
  if (tid < 256) {
    unsigned m = 0;
#pragma unroll
    for (int j = 0; j < 16; ++j)
      m |= (wid[((g * 16 + j) << 8) + tid] != 0) ? (1u << j) : 0u;
    mask16[tid] = m;
  }

  // persistent Wh kk0..3 (32 frags = 128 regs; compiler parks in AGPRs)
  f16x8 regB[32];
#pragma unroll
  for (int kk = 0; kk < 4; ++kk)
#pragma unroll
    for (int j2 = 0; j2 < 8; ++j2)
      regB[kk * 8 + j2] = *(const f16x8*)(whp_c + ((size_t)(kk * 64 + ntg_of(w, j2)) << 10) + (lane << 4));

  // stream landing buffers for kk6/kk7: loaded one step ahead (prologue = k=0)
  f16x8 sb6[8], sb7[8];
#pragma unroll
  for (int j2 = 0; j2 < 8; ++j2) {
    sb6[j2] = *(const f16x8*)(whp_c + ((size_t)(6 * 64 + ntg_of(w, j2)) << 10) + (lane << 4));
    sb7[j2] = *(const f16x8*)(whp_c + ((size_t)(7 * 64 + ntg_of(w, j2)) << 10) + (lane << 4));
  }

  float c[8], hreg[8];
#pragma unroll
  for (int i = 0; i < 8; ++i) { c[i] = 0.f; hreg[i] = 0.f; }

  __syncthreads();

#pragma unroll 1
  for (int k = 0; k < 256; ++k) {
    const int t_in = reverse ? (255 - k) : k;
    const f16* hc = hbuf + (k & 1) * 4224;
    f16*       hn = hbuf + ((k & 1) ^ 1) * 4224;

    // 1) in-step xW loads (packed f16x4; consumed at gates ~>1000cy later)
    f16x4 xwc[2][4];
#pragma unroll
    for (int p = 0; p < 2; ++p)
#pragma unroll
      for (int j = 0; j < 4; ++j)
        xwc[p][j] = *(const f16x4*)(xWp + (size_t)(((g * 16 + rg * 4 + j) << 8) + t_in) * 1024
                                    + ((ct0 + p) * 16 + r0) * 4);

    // 2) MFMA kk0-3 (REG/AGPR)
    f32x4 acc[8] = {};
#pragma unroll
    for (int kk = 0; kk < 4; ++kk) {
      const f16x8 a = *(const f16x8*)&hc[r0 * 264 + kk * 32 + rg * 8];
#pragma unroll
      for (int j2 = 0; j2 < 8; ++j2)
        acc[j2] = __builtin_amdgcn_mfma_f32_16x16x32_f16(a, regB[kk * 8 + j2], acc[j2], 0, 0, 0);
    }

    // 3) MFMA kk4-5 (LDS)
#pragma unroll
    for (int kk = 4; kk < 6; ++kk) {
      const f16x8 a = *(const f16x8*)&hc[r0 * 264 + kk * 32 + rg * 8];
#pragma unroll
      for (int j2 = 0; j2 < 8; ++j2) {
        const f16x8 b8 = *(const f16x8*)(smem + ((size_t)((kk - 4) * 64 + ntg_of(w, j2)) << 10) + (lane << 4));
        acc[j2] = __builtin_amdgcn_mfma_f32_16x16x32_f16(a, b8, acc[j2], 0, 0, 0);
      }
    }

    // 4) MFMA kk6, kk7 (streamed values loaded LAST step -> no vmcnt wait)
    {
      const f16x8 a6 = *(const f16x8*)&hc[r0 * 264 + 6 * 32 + rg * 8];
#pragma unroll
      for (int j2 = 0; j2 < 8; ++j2)
        acc[j2] = __builtin_amdgcn_mfma_f32_16x16x32_f16(a6, sb6[j2], acc[j2], 0, 0, 0);
      const f16x8 a7 = *(const f16x8*)&hc[r0 * 264 + 7 * 32 + rg * 8];
#pragma unroll
      for (int j2 = 0; j2 < 8; ++j2)
        acc[j2] = __builtin_amdgcn_mfma_f32_16x16x32_f16(a7, sb7[j2], acc[j2], 0, 0, 0);
    }

    // 5) issue NEXT step's kk6-7 stream loads now (full-step slack: gates +
    //    publish + barrier + kk0-5 of next step cover the ~2000cy landing).
    //    sched_barrier sandwich pins placement here (no hoist to step top,
    //    no sink below gates).
    __builtin_amdgcn_sched_barrier(0);
#pragma unroll
    for (int j2 = 0; j2 < 8; ++j2) {
      sb6[j2] = *(const f16x8*)(whp_c + ((size_t)(6 * 64 + ntg_of(w, j2)) << 10) + (lane << 4));
      sb7[j2] = *(const f16x8*)(whp_c + ((size_t)(7 * 64 + ntg_of(w, j2)) << 10) + (lane << 4));
    }
    __builtin_amdgcn_sched_barrier(0);

    // 6) gates (f32) with mask bits from LDS; state update
    const unsigned mw = mask16[t_in];
#pragma unroll
    for (int p = 0; p < 2; ++p) {
#pragma unroll
      for (int j = 0; j < 4; ++j) {
        const int idx = p * 4 + j;
        const float zi = acc[0 + p][j] + (float)xwc[p][j][0];
        const float zf = acc[2 + p][j] + (float)xwc[p][j][1];
        const float zc = acc[4 + p][j] + (float)xwc[p][j][2];
        const float zo = acc[6 + p][j] + (float)xwc[p][j][3];
        const float ig = fast_sigmoid(zi);
        const float fg = fast_sigmoid(zf);
        const float og = fast_sigmoid(zo);
        const float cb = fast_tanh(zc);
        const float cn = fg * c[idx] + ig * cb;
        const float hv_ = og * fast_tanh(cn);
        const bool  m  = ((mw >> (rg * 4 + j)) & 1u) != 0u;
        c[idx]    = m ? cn : c[idx];
        hreg[idx] = m ? hv_ : hreg[idx];
      }
    }

    // 7) publish H_{k+1} (LDS) + out store (f16, fire-and-forget)
#pragma unroll
    for (int p = 0; p < 2; ++p)
#pragma unroll
      for (int j = 0; j < 4; ++j) {
        const f16 hv = (f16)hreg[p * 4 + j];
        hn[(rg * 4 + j) * 264 + (ct0 + p) * 16 + r0] = hv;
        out[((size_t)((g * 16 + rg * 4 + j) << 8) + k) * 256 + (ct0 + p) * 16 + r0] = hv;
      }

    // 8) one lgkm-only barrier (vmcnt — including the step-ahead stream —
    //    stays in flight across it)
    __builtin_amdgcn_sched_barrier(0);
    asm volatile("s_waitcnt lgkmcnt(0)\n\ts_barrier" ::: "memory");
    __builtin_amdgcn_sched_barrier(0);
  }
}

// ---------------------------------------------------------------------------
// final: softmax((o6+o7) @ Wd + bd) -> f32 out [16384][128]   (o* are f16)
// ---------------------------------------------------------------------------
__global__ __launch_bounds__(512, 2) void final_k(const f16* __restrict__ o0,
                                                  const f16* __restrict__ o1,
                                                  const f16* __restrict__ wdpf,
                                                  const float* __restrict__ bd,
                                                  float* __restrict__ outp) {
  const int tid = threadIdx.x, lane = tid & 63, w = tid >> 6;
  const int rbase = blockIdx.x * 128 + w * 16;
  const char* wdpf_c = (const char*)wdpf;

  f32x4 acc[8] = {};
#pragma unroll
  for (int kk = 0; kk < 8; ++kk) {
    const int r  = rbase + (lane & 15);
    const int k0 = kk * 32 + (lane >> 4) * 8;
    const f16x8 x = *(const f16x8*)(o0 + (size_t)r * 256 + k0);
    const f16x8 y = *(const f16x8*)(o1 + (size_t)r * 256 + k0);
    const f16x8 a = x + y;
#pragma unroll
    for (int nt = 0; nt < 8; ++nt) {
      const f16x8 b = *(const f16x8*)(wdpf_c + ((size_t)(kk * 8 + nt) << 10) + (lane << 4));
      acc[nt] = __builtin_amdgcn_mfma_f32_16x16x32_f16(a, b, acc[nt], 0, 0, 0);
    }
  }

  float vb[8];
#pragma unroll
  for (int nt = 0; nt < 8; ++nt) vb[nt] = bd[nt * 16 + (lane & 15)];

#pragma unroll
  for (int j = 0; j < 4; ++j) {
    float v[8];
#pragma unroll
    for (int nt = 0; nt < 8; ++nt) v[nt] = acc[nt][j] + vb[nt];
    float mx = v[0];
#pragma unroll
    for (int nt = 1; nt < 8; ++nt) mx = fmaxf(mx, v[nt]);
#pragma unroll
    for (int m = 1; m < 16; m <<= 1) mx = fmaxf(mx, __shfl_xor(mx, m, 64));
    float s = 0.f;
#pragma unroll
    for (int nt = 0; nt < 8; ++nt) {
      v[nt] = __builtin_amdgcn_exp2f(1.44269504f * (v[nt] - mx));
      s += v[nt];
    }
#pragma unroll
    for (int m = 1; m < 16; m <<= 1) s += __shfl_xor(s, m, 64);
    const float rs = __builtin_amdgcn_rcpf(s);
    const int r = rbase + (lane >> 4) * 4 + j;
#pragma unroll
    for (int nt = 0; nt < 8; ++nt)
      outp[(size_t)r * 128 + nt * 16 + (lane & 15)] = v[nt] * rs;
  }
}

// ---------------------------------------------------------------------------
extern "C" void kernel_launch(void* const* d_in, const int* in_sizes, int n_in,
                              void* d_out, int out_size, void* d_ws, size_t ws_size,
                              hipStream_t stream) {
  const int*   wid  = (const int*)d_in[0];
  const int*   pid  = (const int*)d_in[1];
  const float* emb1 = (const float*)d_in[2];
  const float* emb2 = (const float*)d_in[3];
  const float* Wis  = (const float*)d_in[4];
  const float* Whs  = (const float*)d_in[5];
  const float* bs   = (const float*)d_in[6];
  const float* Wd   = (const float*)d_in[7];
  const float* bd   = (const float*)d_in[8];

  char* ws = (char*)d_ws;
  f16* Whp  = (f16*)(ws + 0);          //  4,194,304
  f16* Wipf = (f16*)(ws + 4194304);    //  4,194,304
  f16* Wdpf = (f16*)(ws + 8388608);    //     65,536
  f16* X    = (f16*)(ws + 8454144);    //  8,388,608
  f16* xWp  = (f16*)(ws + 16842752);   // 33,554,432
  f16* o0   = (f16*)(ws + 50397184);   //  8,388,608
  f16* o1   = (f16*)(ws + 58785792);   //  8,388,608

  hipFuncSetAttribute((const void*)gemm_xw,    hipFuncAttributeMaxDynamicSharedMemorySize, 65536);
  hipFuncSetAttribute((const void*)lstm_layer, hipFuncAttributeMaxDynamicSharedMemorySize, 148992);

  pack_frags<<<1024, 256, 0, stream>>>(Whs, Whp, 64);
  pack_frags<<<1024, 256, 0, stream>>>(Wis, Wipf, 64);
  pack_frags<<<16,   256, 0, stream>>>(Wd,  Wdpf, 8);
  embed_k<<<16384, 128, 0, stream>>>(wid, pid, emb1, emb2, X);

  f16* obuf[2] = {o0, o1};
  for (int L = 0; L < 8; ++L) {
    const f16* xin = X;
    if (L == 1) {
      xin = o0;                                   // identity input, same layout
    } else if (L >= 2) {
      make_input<<<2048, 256, 0, stream>>>(obuf[L & 1], obuf[(L - 1) & 1], X);
    }
    gemm_xw<<<dim3(8, 128), 512, 65536, stream>>>(xin, Wipf + (size_t)L * 262144,
                                                  bs + L * 1024, xWp);
    lstm_layer<<<4, 512, 148992, stream>>>(xWp, wid, Whp + (size_t)L * 262144,
                                           obuf[L & 1], L & 1);
  }
  final_k<<<128, 512, 0, stream>>>(o0, o1, Wdpf, bd, (float*)d_out);
}